// Round 3
// baseline (387.996 us; speedup 1.0000x reference)
//
#include <hip/hip_runtime.h>
#include <hip/hip_cooperative_groups.h>

#pragma clang fp contract(off)

namespace cg = cooperative_groups;

#define H_ 192
#define W_ 192
#define HW_ (192 * 192)
#define NSC 3
#define NCAND (NSC * HW_)
#define CCH 256
#define KMAX 2048
#define NBIN 4096
#define NBLK 432  /* NCAND / 256 */

// d_out layout (floats), in reference return order:
// keypoints [2048,2], descriptors [2048,256], scores [2048], det0/1/2 [192,192]
#define KP_OFF 0
#define DESC_OFF (KMAX * 2)
#define SC_OFF (DESC_OFF + KMAX * CCH)
#define DET_OFF (SC_OFF + KMAX)

typedef unsigned long long u64;
typedef unsigned int u32;

// ws layout (bytes):
//      0 : fin keys   u64[NCAND]      884736
// 884736 : cnts       u32[16]         64      [0]=nfin [2]=m(scattered)
// 884800 : slotinfo   float4[KMAX]    32768   (zeroed in-kernel: det==0 -> padding row)
// 917568 : ghist      u32[NBIN]       16384   (zeroed in-kernel)
// 933952 : SARR       u32[NBIN+1]     16448   (written by scan phase)
// 950400 : cursor     u32[NBIN]       16384   (written by scan phase)
// 966784 : surv       u64[NCAND]      884736  (bin-grouped keys)
#define CNT_OFF 884736
#define SLOT_OFF 884800
#define GH_OFF 917568
#define SARR_OFF 933952
#define CUR_OFF 950400
#define SURV_OFF 966784
#define ZERO_WORDS 12304  /* (64 + 32768 + 16384) / 4, contiguous at CNT_OFF */

// Order-monotone, DISTRIBUTION-AWARE bin of the key's high word (positive
// ordered-float bits). det = max of 9 iid U[0,1) -> ~99.8% of mass in
// [0.5,1): give that range 2048 fine bins (mantissa bits 22..12); coarse
// monotone map below. Monotone at boundary: coarse max 0x3EF=1007 < 2048.
__device__ __forceinline__ u32 key_bin(u32 sb) {
    if (sb >= 0xBF800000u) return NBIN - 1;                        // det>=1: safety
    if (sb >= 0xBF000000u) return 2048u + ((sb >> 12) & 0x7FFu);   // det in [0.5,1)
    return (sb >> 20) & 0x7FFu;                                    // det in (0,0.5)
}

// Exact replica of the reference per-pixel math. FP contraction OFF for this
// TU -> float ops match numpy bit-for-bit. OOB taps read as 0.0, INCLUDING in
// the max: provably identical to the -inf-padded maxpool because scores>=0
// (zeros can't beat c>0; c==0 gives det=0 either way). Branchless.
__device__ __forceinline__ void newton_pixel(const float* __restrict__ sm, int i, int j,
                                             float& det, float& ki, float& kj, bool& valid) {
    float v[3][3];
#pragma unroll
    for (int a = 0; a < 3; ++a) {
#pragma unroll
        for (int b = 0; b < 3; ++b) {
            int ii = i + a - 1, jj = j + b - 1;
            bool in = (ii >= 0) && (ii < H_) && (jj >= 0) && (jj < W_);
            v[a][b] = in ? sm[ii * W_ + jj] : 0.0f;
        }
    }
    float c = v[1][1];
    float mx = v[0][0];
    mx = fmaxf(mx, v[0][1]); mx = fmaxf(mx, v[0][2]);
    mx = fmaxf(mx, v[1][0]); mx = fmaxf(mx, c);
    mx = fmaxf(mx, v[1][2]); mx = fmaxf(mx, v[2][0]);
    mx = fmaxf(mx, v[2][1]); mx = fmaxf(mx, v[2][2]);
    det = (mx == c) ? c : 0.0f;
    float di  = -0.5f * v[0][1] + 0.5f * v[2][1];
    float dj  = -0.5f * v[1][0] + 0.5f * v[1][2];
    float dii = v[0][1] - 2.0f * c + v[2][1];
    float djj = v[1][0] - 2.0f * c + v[1][2];
    float dij = 0.25f * v[0][0] - 0.25f * v[0][2] - 0.25f * v[2][0] + 0.25f * v[2][2];
    float dd = dii * djj - dij * dij;
    if (dd == 0.0f) dd = 1e-20f;
    float step_i = -(djj * di - dij * dj) / dd;
    float step_j = -(-dij * di + dii * dj) / dd;
    valid = (det != 0.0f) && (fabsf(step_i) < 0.5f) && (fabsf(step_j) < 0.5f);
    ki = valid ? ((float)i + step_i) : 0.0f;
    kj = valid ? ((float)j + step_j) : 0.0f;
    float i0 = floorf(ki), j0 = floorf(kj);
    valid = valid && (i0 >= 0.0f) && (j0 >= 0.0f) &&
            (i0 + 1.0f <= (float)(H_ - 1)) && (j0 + 1.0f <= (float)(W_ - 1));
}

__device__ __forceinline__ void decode_gid(u32 gid, int& s, int& i, int& j) {
    s = (int)(gid / HW_);
    int rem = (int)gid - s * HW_;
    i = rem / W_;
    j = rem - i * W_;
}

// Single cooperative kernel: all six former dispatches as phases separated by
// grid.sync() (device-scope barrier + fences; handles per-XCD L2 visibility).
// Every phase keeps full grid-wide parallelism — the round-1 lesson: never
// serialize a latency-bound phase onto one block. One block (scan) IS serial,
// but it's 16 KB of LDS work (~1-2 us) while others wait at the barrier.
// 432 blocks x 256 thr co-resident at 2 blocks/CU (launch_bounds caps VGPR<=128;
// LDS 17.5 KB/block -> fine).
__global__ __launch_bounds__(256, 2) void mega_kernel(
    const float* __restrict__ f0, const float* __restrict__ f1, const float* __restrict__ f2,
    const float* __restrict__ s0, const float* __restrict__ s1, const float* __restrict__ s2,
    float* __restrict__ out, u64* __restrict__ fin, u32* __restrict__ cnts,
    float4* __restrict__ slot, u32* __restrict__ ghist, u32* __restrict__ sarr,
    u32* __restrict__ cursor, u64* __restrict__ surv) {
    cg::grid_group grid = cg::this_grid();
    __shared__ u32 ls[NBIN + 1];
    __shared__ u32 lT[256];
    int tid = threadIdx.x;
    int gid = blockIdx.x * 256 + tid;

    // ---- phase 0: zero cnts + slotinfo + ghist (contiguous, 1 word/thread) ----
    if (gid < ZERO_WORDS) cnts[gid] = 0u;
    grid.sync();

    // ---- phase 1: cand — NMS/Newton, det maps, key append, bin histogram ----
    {
        if (tid == 0) ls[0] = 0;  // lcnt
        __syncthreads();
        bool valid = false;
        u64 key = 0;
        int s, i, j;
        decode_gid((u32)gid, s, i, j);
        const float* sm = (s == 0) ? s0 : (s == 1) ? s1 : s2;
        float det, ki, kj;
        newton_pixel(sm, i, j, det, ki, kj, valid);
        out[DET_OFF + gid] = det;
        if (valid) {
            u32 sb = __float_as_uint(det) | 0x80000000u;  // det>0: ordered bits
            key = ((u64)sb << 32) | (u64)(0xFFFFFFFFu - (u32)gid);  // ties: lower idx first
            atomicAdd(&ghist[key_bin(sb)], 1u);
        }
        u32 lpos = 0;
        if (valid) lpos = atomicAdd(&ls[0], 1u);
        __syncthreads();
        if (tid == 0 && ls[0] > 0) ls[1] = atomicAdd(&cnts[0], ls[0]);
        __syncthreads();
        if (valid) fin[ls[1] + lpos] = key;
    }
    grid.sync();

    // ---- phase 2 (block 0 only): inclusive suffix scan S[b]=#keys bin>=b ----
    if (blockIdx.x == 0) {
        u32 chunk[16];
        u32 acc = 0;
#pragma unroll
        for (int k = 15; k >= 0; --k) {
            acc += ghist[tid * 16 + k];
            chunk[k] = acc;  // suffix within chunk
        }
        lT[tid] = acc;
        __syncthreads();
        for (int off = 1; off < 256; off <<= 1) {
            u32 v = lT[tid] + ((tid + off < 256) ? lT[tid + off] : 0u);
            __syncthreads();
            lT[tid] = v;
            __syncthreads();
        }
        u32 add = (tid < 255) ? lT[tid + 1] : 0u;  // exclusive suffix of later chunks
#pragma unroll
        for (int k = 0; k < 16; ++k) ls[tid * 16 + k] = chunk[k] + add;
        if (tid == 0) ls[NBIN] = 0;
        __syncthreads();
#pragma unroll
        for (int k = 0; k < 16; ++k) {
            u32 b = tid * 16 + k;
            sarr[b] = ls[b];
            cursor[b] = ls[b + 1];
            if (ls[b + 1] < KMAX && (b == 0 || ls[b] >= KMAX)) cnts[2] = ls[b];  // m
        }
        if (tid == 0) sarr[NBIN] = 0;
    }
    grid.sync();

    // ---- phase 3: scatter survivors into bin-grouped order ----
    {
        u32 n = cnts[0];  // <= NCAND = grid size: one key/thread
        if ((u32)gid < n) {
            u64 key = fin[gid];
            u32 b = key_bin((u32)(key >> 32));
            if (sarr[b + 1] < KMAX) {
                u32 pos = atomicAdd(&cursor[b], 1u);
                surv[pos] = key;
            }
        }
    }
    grid.sync();

    // ---- phase 4: exact rank within bin segment; winners write slot info ----
    {
        u32 m = cnts[2];  // <= n: one key/thread, full grid TLP for the scans
        if ((u32)gid < m) {
            u64 key = surv[gid];
            u32 b = key_bin((u32)(key >> 32));
            u32 lo = sarr[b + 1], hi = sarr[b];
            u32 rank = lo;
            for (u32 q = lo; q < hi; ++q) rank += (surv[q] > key) ? 1u : 0u;
            if (rank < KMAX) {
                u32 g2 = 0xFFFFFFFFu - (u32)(key & 0xFFFFFFFFull);
                int s, i, j;
                decode_gid(g2, s, i, j);
                const float* sm = (s == 0) ? s0 : (s == 1) ? s1 : s2;
                float det, ki, kj;
                bool valid;
                newton_pixel(sm, i, j, det, ki, kj, valid);
                slot[rank] = make_float4(ki, kj, det, (float)s);
            }
        }
    }
    grid.sync();

    // ---- phase 5: one WAVE per output slot (1728 waves cover 2048 slots) ----
    {
        int lane = tid & 63;
        int w = blockIdx.x * 4 + (tid >> 6);
        for (int r = w; r < KMAX; r += NBLK * 4) {
            float4 info = slot[r];
            bool pad = (info.z == 0.0f);
            float ki = info.x, kj = info.y;
            int s = (int)info.w;
            const float* feat = (s == 0) ? f0 : (s == 1) ? f1 : f2;
            int i0 = (int)floorf(ki), j0 = (int)floorf(kj);
            float wi = ki - (float)i0;
            float wj = kj - (float)j0;
            const float* p = feat + (size_t)lane * HW_ + i0 * W_ + j0;
            float d[4];
            float sq = 0.0f;
#pragma unroll
            for (int k = 0; k < 4; ++k) {
                const float* q = p + (size_t)k * 64 * HW_;
                float f00 = q[0], f01 = q[1], f10 = q[W_], f11 = q[W_ + 1];
                d[k] = f00 * (1.0f - wi) * (1.0f - wj) + f01 * (1.0f - wi) * wj +
                       f10 * wi * (1.0f - wj) + f11 * wi * wj;
                sq += d[k] * d[k];
            }
#pragma unroll
            for (int o = 1; o < 64; o <<= 1) sq += __shfl_xor(sq, o, 64);
            float norm = fmaxf(sqrtf(sq), 1e-12f);
#pragma unroll
            for (int k = 0; k < 4; ++k)
                out[DESC_OFF + r * CCH + k * 64 + lane] = pad ? 0.0f : d[k] / norm;
            if (lane == 0) {
                float x = kj, y = ki;
#pragma unroll
                for (int u = 0; u < 4; ++u) { x = x * 2.0f + 0.5f; y = y * 2.0f + 0.5f; }
                out[SC_OFF + r] = pad ? 0.0f : info.z;
                out[KP_OFF + r * 2 + 0] = pad ? 0.0f : x;  // (x=col, y=row)
                out[KP_OFF + r * 2 + 1] = pad ? 0.0f : y;
            }
        }
    }
}

extern "C" void kernel_launch(void* const* d_in, const int* in_sizes, int n_in,
                              void* d_out, int out_size, void* d_ws, size_t ws_size,
                              hipStream_t stream) {
    const float* f0 = (const float*)d_in[0];
    const float* f1 = (const float*)d_in[1];
    const float* f2 = (const float*)d_in[2];
    const float* s0 = (const float*)d_in[3];
    const float* s1 = (const float*)d_in[4];
    const float* s2 = (const float*)d_in[5];
    float* out = (float*)d_out;

    char* ws = (char*)d_ws;
    u64* fin = (u64*)ws;
    u32* cnts = (u32*)(ws + CNT_OFF);
    float4* slot = (float4*)(ws + SLOT_OFF);
    u32* ghist = (u32*)(ws + GH_OFF);
    u32* sarr = (u32*)(ws + SARR_OFF);
    u32* cursor = (u32*)(ws + CUR_OFF);
    u64* surv = (u64*)(ws + SURV_OFF);

    void* args[] = {&f0, &f1, &f2, &s0, &s1, &s2, &out, &fin, &cnts,
                    &slot, &ghist, &sarr, &cursor, &surv};
    hipLaunchCooperativeKernel((const void*)mega_kernel, dim3(NBLK), dim3(256),
                               args, 0, stream);
}

// Round 4
// 157.189 us; speedup vs baseline: 2.4683x; 2.4683x over previous
//
#include <hip/hip_runtime.h>

#pragma clang fp contract(off)

#define H_ 192
#define W_ 192
#define HW_ (192 * 192)
#define NSC 3
#define NCAND (NSC * HW_)
#define CCH 256
#define KMAX 2048
#define NBIN 4096

// d_out layout (floats), in reference return order:
// keypoints [2048,2], descriptors [2048,256], scores [2048], det0/1/2 [192,192]
#define KP_OFF 0
#define DESC_OFF (KMAX * 2)
#define SC_OFF (DESC_OFF + KMAX * CCH)
#define DET_OFF (SC_OFF + KMAX)

typedef unsigned long long u64;
typedef unsigned int u32;

// ws layout (bytes):
//      0 : fin keys   u64[NCAND]      884736
// 884736 : cnts       u32[16]         64      [0]=nfin
// 884800 : ghist      u32[NBIN]       16384   (memset 0)
// 901184 : cursor     u32[NBIN]       16384   (memset 0; zero-based per-bin)
// 917568 : surv       u64[NCAND]      884736  (bin-grouped keys)
// memset covers cnts+ghist+cursor contiguously: 64+16384+16384 = 32832 B.
// No slot array, no global SARR: consumers recompute the 16 KB suffix scan in
// LDS (redundancy instead of synchronization -- r1: never one-block a phase;
// r3: grid.sync costs ~45us/sync on 8 XCDs).
#define CNT_OFF 884736
#define GH_OFF 884800
#define CUR_OFF 901184
#define SURV_OFF 917568
#define ZERO_BYTES 32832

// Order-monotone, DISTRIBUTION-AWARE bin of the key's high word (positive
// ordered-float bits). det = max of 9 iid U[0,1) -> ~99.8% of mass in
// [0.5,1): give that range 2048 fine bins (mantissa bits 22..12); coarse
// monotone map below. Monotone at boundary: coarse max 0x3EF=1007 < 2048.
__device__ __forceinline__ u32 key_bin(u32 sb) {
    if (sb >= 0xBF800000u) return NBIN - 1;                        // det>=1: safety
    if (sb >= 0xBF000000u) return 2048u + ((sb >> 12) & 0x7FFu);   // det in [0.5,1)
    return (sb >> 20) & 0x7FFu;                                    // det in (0,0.5)
}

// Exact replica of the reference per-pixel math. FP contraction OFF for this
// TU -> float ops match numpy bit-for-bit. OOB taps read as 0.0, INCLUDING in
// the max: provably identical to the -inf-padded maxpool because scores>=0
// (zeros can't beat c>0; c==0 gives det=0 either way). Branchless.
__device__ __forceinline__ void newton_pixel(const float* __restrict__ sm, int i, int j,
                                             float& det, float& ki, float& kj, bool& valid) {
    float v[3][3];
#pragma unroll
    for (int a = 0; a < 3; ++a) {
#pragma unroll
        for (int b = 0; b < 3; ++b) {
            int ii = i + a - 1, jj = j + b - 1;
            bool in = (ii >= 0) && (ii < H_) && (jj >= 0) && (jj < W_);
            v[a][b] = in ? sm[ii * W_ + jj] : 0.0f;
        }
    }
    float c = v[1][1];
    float mx = v[0][0];
    mx = fmaxf(mx, v[0][1]); mx = fmaxf(mx, v[0][2]);
    mx = fmaxf(mx, v[1][0]); mx = fmaxf(mx, c);
    mx = fmaxf(mx, v[1][2]); mx = fmaxf(mx, v[2][0]);
    mx = fmaxf(mx, v[2][1]); mx = fmaxf(mx, v[2][2]);
    det = (mx == c) ? c : 0.0f;
    float di  = -0.5f * v[0][1] + 0.5f * v[2][1];
    float dj  = -0.5f * v[1][0] + 0.5f * v[1][2];
    float dii = v[0][1] - 2.0f * c + v[2][1];
    float djj = v[1][0] - 2.0f * c + v[1][2];
    float dij = 0.25f * v[0][0] - 0.25f * v[0][2] - 0.25f * v[2][0] + 0.25f * v[2][2];
    float dd = dii * djj - dij * dij;
    if (dd == 0.0f) dd = 1e-20f;
    float step_i = -(djj * di - dij * dj) / dd;
    float step_j = -(-dij * di + dii * dj) / dd;
    valid = (det != 0.0f) && (fabsf(step_i) < 0.5f) && (fabsf(step_j) < 0.5f);
    ki = valid ? ((float)i + step_i) : 0.0f;
    kj = valid ? ((float)j + step_j) : 0.0f;
    float i0 = floorf(ki), j0 = floorf(kj);
    valid = valid && (i0 >= 0.0f) && (j0 >= 0.0f) &&
            (i0 + 1.0f <= (float)(H_ - 1)) && (j0 + 1.0f <= (float)(W_ - 1));
}

__device__ __forceinline__ void decode_gid(u32 gid, int& s, int& i, int& j) {
    s = (int)(gid / HW_);
    int rem = (int)gid - s * HW_;
    i = rem / W_;
    j = rem - i * W_;
}

// Per-block redundant inclusive suffix scan of ghist into LDS:
// ls[b] = S[b] = #keys with bin >= b; ls[NBIN] = 0. ~16 KB L2-hot reads,
// ~2 us; cheaper than a dispatch boundary or a grid sync.
__device__ __forceinline__ void lds_suffix_scan(const u32* __restrict__ ghist,
                                                u32* ls, u32* lT) {
    int t = threadIdx.x;
    u32 chunk[16];
    u32 acc = 0;
#pragma unroll
    for (int k = 15; k >= 0; --k) {
        acc += ghist[t * 16 + k];
        chunk[k] = acc;  // suffix within chunk
    }
    lT[t] = acc;
    __syncthreads();
    // inclusive suffix scan of 256 chunk totals (Hillis-Steele)
    for (int off = 1; off < 256; off <<= 1) {
        u32 v = lT[t] + ((t + off < 256) ? lT[t + off] : 0u);
        __syncthreads();
        lT[t] = v;
        __syncthreads();
    }
    u32 add = (t < 255) ? lT[t + 1] : 0u;  // exclusive suffix of later chunks
#pragma unroll
    for (int k = 0; k < 16; ++k) ls[t * 16 + k] = chunk[k] + add;
    if (t == 0) ls[NBIN] = 0;
    __syncthreads();
}

// Kernel 1: per-pixel NMS/Newton; det maps; append valid keys; global-atomic
// score-bin histogram (~12k valid keys over ~2k hot bins -> no contention).
__global__ __launch_bounds__(256) void cand_kernel(
    const float* __restrict__ s0, const float* __restrict__ s1, const float* __restrict__ s2,
    float* __restrict__ out, u64* __restrict__ fin, u32* __restrict__ cnts,
    u32* __restrict__ ghist) {
    __shared__ u32 lcnt, base;
    int tid = threadIdx.x;
    if (tid == 0) lcnt = 0;
    __syncthreads();
    int t = blockIdx.x * 256 + tid;
    bool valid = false;
    u64 key = 0;
    {
        int s, i, j;
        decode_gid((u32)t, s, i, j);
        const float* sm = (s == 0) ? s0 : (s == 1) ? s1 : s2;
        float det, ki, kj;
        newton_pixel(sm, i, j, det, ki, kj, valid);
        out[DET_OFF + t] = det;
        if (valid) {
            u32 sb = __float_as_uint(det) | 0x80000000u;  // det>0: ordered bits
            key = ((u64)sb << 32) | (u64)(0xFFFFFFFFu - (u32)t);  // ties: lower idx first
            atomicAdd(&ghist[key_bin(sb)], 1u);
        }
    }
    u32 lpos = 0;
    if (valid) lpos = atomicAdd(&lcnt, 1u);
    __syncthreads();
    if (tid == 0 && lcnt > 0) base = atomicAdd(&cnts[0], lcnt);
    __syncthreads();
    if (valid) fin[base + lpos] = key;
}

// Kernel 2 (was scan+scatter): each block privately recomputes the suffix scan
// in LDS, then scatters its grid-stride keys whose bin segment base < KMAX to
// surv[S[b+1] + cursor0[b]++] (cursor zero-based, memset-zeroed).
__global__ __launch_bounds__(256) void scatter_kernel(
    const u64* __restrict__ fin, const u32* __restrict__ ghist, u32* __restrict__ cursor,
    const u32* __restrict__ cnts, u64* __restrict__ surv) {
    __shared__ u32 ls[NBIN + 1];
    __shared__ u32 lT[256];
    lds_suffix_scan(ghist, ls, lT);
    u32 n = cnts[0];
    for (u32 idx = blockIdx.x * 256 + threadIdx.x; idx < n; idx += 64 * 256) {
        u64 key = fin[idx];
        u32 b = key_bin((u32)(key >> 32));
        u32 seglo = ls[b + 1];
        if (seglo < KMAX) {
            u32 off = atomicAdd(&cursor[b], 1u);
            surv[seglo + off] = key;
        }
    }
}

// Kernel 3 (was rank+output): one WAVE per slot r (4 waves/block, 512 blocks).
// Block recomputes the suffix scan in LDS; each wave binary-searches the bin
// whose segment [S[b+1],S[b]) contains global rank r, identifies the rank-r
// key inside that ~13-key segment (distinct keys -> segment ranks are a
// permutation of [lo,hi): exactly one match), recomputes its newton state, and
// does the bilinear gather + L2-normalize. Slots r >= min(n,KMAX) are padding.
__global__ __launch_bounds__(256) void output_kernel(
    const u64* __restrict__ surv, const u32* __restrict__ ghist,
    const float* __restrict__ s0, const float* __restrict__ s1, const float* __restrict__ s2,
    const float* __restrict__ f0, const float* __restrict__ f1, const float* __restrict__ f2,
    float* __restrict__ out) {
    __shared__ u32 ls[NBIN + 1];
    __shared__ u32 lT[256];
    lds_suffix_scan(ghist, ls, lT);
    int tid = threadIdx.x;
    int lane = tid & 63;
    int r = blockIdx.x * 4 + (tid >> 6);
    u32 n = ls[0];
    u32 nwin = (n < KMAX) ? n : KMAX;
    if ((u32)r >= nwin) {  // padding row (whole wave uniform; no more barriers)
#pragma unroll
        for (int k = 0; k < 4; ++k) out[DESC_OFF + r * CCH + k * 64 + lane] = 0.0f;
        if (lane == 0) {
            out[SC_OFF + r] = 0.0f;
            out[KP_OFF + r * 2 + 0] = 0.0f;
            out[KP_OFF + r * 2 + 1] = 0.0f;
        }
        return;
    }
    // binary search: largest b with S[b] > r  (S non-increasing, S[0]=n>r, S[NBIN]=0)
    u32 blo = 0, bhi = NBIN;
    while (bhi - blo > 1) {
        u32 mid = (blo + bhi) >> 1;
        if (ls[mid] > (u32)r) blo = mid; else bhi = mid;
    }
    u32 b = blo;
    u32 seglo = ls[b + 1], seghi = ls[b];  // S[b+1] <= r < S[b]
    // identify the key with exact rank r (lane-strided over the segment)
    u64 mykey = 0;
    bool mine = false;
    for (u32 p = seglo + (u32)lane; p < seghi; p += 64) {
        u64 key = surv[p];
        u32 rk = seglo;
        for (u32 q = seglo; q < seghi; ++q) rk += (surv[q] > key) ? 1u : 0u;
        if (rk == (u32)r) { mykey = key; mine = true; }
    }
    u64 bal = __ballot(mine);
    int src = __ffsll((unsigned long long)bal) - 1;
    u32 klo = (u32)__shfl((int)(u32)(mykey & 0xFFFFFFFFull), src, 64);
    u32 khi = (u32)__shfl((int)(u32)(mykey >> 32), src, 64);
    u64 key = ((u64)khi << 32) | (u64)klo;
    // recompute newton state for the winner (9 broadcast loads, all lanes)
    u32 gid = 0xFFFFFFFFu - (u32)(key & 0xFFFFFFFFull);
    int s, i, j;
    decode_gid(gid, s, i, j);
    const float* sm = (s == 0) ? s0 : (s == 1) ? s1 : s2;
    float det, ki, kj;
    bool valid;
    newton_pixel(sm, i, j, det, ki, kj, valid);
    // bilinear gather + normalize: lane owns channels {lane, +64, +128, +192}
    const float* feat = (s == 0) ? f0 : (s == 1) ? f1 : f2;
    int i0 = (int)floorf(ki), j0 = (int)floorf(kj);
    float wi = ki - (float)i0;
    float wj = kj - (float)j0;
    const float* p = feat + (size_t)lane * HW_ + i0 * W_ + j0;
    float d[4];
    float sq = 0.0f;
#pragma unroll
    for (int k = 0; k < 4; ++k) {
        const float* q = p + (size_t)k * 64 * HW_;
        float f00 = q[0], f01 = q[1], f10 = q[W_], f11 = q[W_ + 1];
        d[k] = f00 * (1.0f - wi) * (1.0f - wj) + f01 * (1.0f - wi) * wj +
               f10 * wi * (1.0f - wj) + f11 * wi * wj;
        sq += d[k] * d[k];
    }
#pragma unroll
    for (int o = 1; o < 64; o <<= 1) sq += __shfl_xor(sq, o, 64);
    float norm = fmaxf(sqrtf(sq), 1e-12f);
#pragma unroll
    for (int k = 0; k < 4; ++k)
        out[DESC_OFF + r * CCH + k * 64 + lane] = d[k] / norm;
    if (lane == 0) {
        float x = kj, y = ki;
#pragma unroll
        for (int u = 0; u < 4; ++u) { x = x * 2.0f + 0.5f; y = y * 2.0f + 0.5f; }
        out[SC_OFF + r] = det;
        out[KP_OFF + r * 2 + 0] = x;  // (x=col, y=row)
        out[KP_OFF + r * 2 + 1] = y;
    }
}

extern "C" void kernel_launch(void* const* d_in, const int* in_sizes, int n_in,
                              void* d_out, int out_size, void* d_ws, size_t ws_size,
                              hipStream_t stream) {
    const float* f0 = (const float*)d_in[0];
    const float* f1 = (const float*)d_in[1];
    const float* f2 = (const float*)d_in[2];
    const float* s0 = (const float*)d_in[3];
    const float* s1 = (const float*)d_in[4];
    const float* s2 = (const float*)d_in[5];
    float* out = (float*)d_out;

    char* ws = (char*)d_ws;
    u64* fin = (u64*)ws;
    u32* cnts = (u32*)(ws + CNT_OFF);
    u32* ghist = (u32*)(ws + GH_OFF);
    u32* cursor = (u32*)(ws + CUR_OFF);
    u64* surv = (u64*)(ws + SURV_OFF);

    // zero cnts + ghist + cursor in one contiguous memset (33 KB)
    hipMemsetAsync(ws + CNT_OFF, 0, ZERO_BYTES, stream);
    cand_kernel<<<NCAND / 256, 256, 0, stream>>>(s0, s1, s2, out, fin, cnts, ghist);
    scatter_kernel<<<64, 256, 0, stream>>>(fin, ghist, cursor, cnts, surv);
    output_kernel<<<KMAX / 4, 256, 0, stream>>>(surv, ghist, s0, s1, s2, f0, f1, f2, out);
}